// Round 6
// baseline (269.740 us; speedup 1.0000x reference)
//
#include <hip/hip_runtime.h>
#include <math.h>

#define N_ATOMS 50000
#define M_NBR   12
#define A_FEA   64
#define B_FEA   41
#define KF      169      // 2*A + B
#define KP      192      // padded K (6 chunks of 32)
#define LDA     200      // LDS row stride in bf16 (400 B -> free 2-way banking)
#define OC      128      // 2*A
#define NROW    600000   // N_ATOMS * M_NBR
#define TR32    32       // rows per GEMM tile
#define NT32    18750    // NROW / 32
#define NT192   3125     // NROW / 192 (16-atom apply tiles)
#define S2S     68       // apply scratch stride (floats)
#define BN_EPS  1e-5f
#define L2E     1.44269504088896340736f
#define LN2     0.693147180559945309417f

// d_ws layout
#define WS_SUM1   0
#define WS_SUMSQ1 128
#define WS_SUM2   256
#define WS_SUMSQ2 320
#define WS_NFLOAT 384
#define WS_GATED_OFF 2048ull
#define GATED_BYTES  ((size_t)NT32 * 512 * 16)   // 153.6 MB of bf16 (uint4 layout)

// Workgroup barrier that drains ONLY LDS ops (lgkmcnt), leaving vmem loads
// in flight across the barrier (R5: measured null vs __syncthreads, kept as
// harmless and potentially useful at higher wave pressure).
#define BAR_LGKM() asm volatile("s_waitcnt lgkmcnt(0)\n\ts_barrier" ::: "memory")

typedef __attribute__((ext_vector_type(8))) short s16x8;
typedef __attribute__((ext_vector_type(4))) float f32x4;

__device__ __forceinline__ float fsigmoid(float x) {
    float e = __builtin_amdgcn_exp2f(-x * L2E);
    return __builtin_amdgcn_rcpf(1.f + e);
}
__device__ __forceinline__ float fsoftplus(float x) {
    float e = __builtin_amdgcn_exp2f(-fabsf(x) * L2E);
    return fmaxf(x, 0.f) + __builtin_amdgcn_logf(1.f + e) * LN2;
}
__device__ __forceinline__ unsigned short f2bf(float f) {
    unsigned int u = __float_as_uint(f);
    u += 0x7FFFu + ((u >> 16) & 1u);     // RNE
    return (unsigned short)(u >> 16);
}
__device__ __forceinline__ unsigned int pack2bf(float lo, float hi) {
    return (unsigned int)f2bf(lo) | ((unsigned int)f2bf(hi) << 16);
}
__device__ __forceinline__ float bf_lo(unsigned int u) { return __uint_as_float(u << 16); }
__device__ __forceinline__ float bf_hi(unsigned int u) { return __uint_as_float(u & 0xFFFF0000u); }

__global__ void k_zero_stats(float* __restrict__ stats) {
    int i = blockIdx.x * blockDim.x + threadIdx.x;
    if (i < WS_NFLOAT) stats[i] = 0.f;
}
__global__ void k_zero(float* __restrict__ dout, float* __restrict__ stats) {
    int i = blockIdx.x * blockDim.x + threadIdx.x;
    int stride = gridDim.x * blockDim.x;
    for (int j = i; j < N_ATOMS * A_FEA; j += stride) dout[j] = 0.f;
    if (i < WS_NFLOAT) stats[i] = 0.f;
}

// ---- register staging state for one 32-row tile ----------------------------
struct TileRegs {
    float4 selfv[2];
    float4 gat[2];
    float4 bond0, bond1;
};

__device__ __forceinline__ void issue_selfbond(TileRegs& R, const float* __restrict__ atom,
                                               const float* __restrict__ nbr,
                                               int rb, int r16, int k4, int tid) {
#pragma unroll
    for (int it = 0; it < 2; ++it) {
        int row = rb + r16 + it * 16;
        R.selfv[it] = *(const float4*)(atom + ((unsigned)row / 12u) * A_FEA + k4);
    }
    const float* bb = nbr + (size_t)rb * B_FEA;   // 1312 floats = 328 float4, 16B-aligned
    R.bond0 = *(const float4*)(bb + (size_t)tid * 4);
    if (tid < 72) R.bond1 = *(const float4*)(bb + (size_t)(256 + tid) * 4);
}
__device__ __forceinline__ void issue_gat(TileRegs& R, const float* __restrict__ atom,
                                          const int nbi[2], int k4) {
#pragma unroll
    for (int it = 0; it < 2; ++it)
        R.gat[it] = *(const float4*)(atom + (unsigned)nbi[it] * A_FEA + k4);
}
__device__ __forceinline__ void write_tile(unsigned short* __restrict__ At,
                                           const TileRegs& R, int r16, int k4, int tid) {
#pragma unroll
    for (int it = 0; it < 2; ++it) {
        int r = r16 + it * 16;
        uint2 u;
        u.x = pack2bf(R.selfv[it].x, R.selfv[it].y);
        u.y = pack2bf(R.selfv[it].z, R.selfv[it].w);
        *(uint2*)&At[r * LDA + k4] = u;
        uint2 v;
        v.x = pack2bf(R.gat[it].x, R.gat[it].y);
        v.y = pack2bf(R.gat[it].z, R.gat[it].w);
        *(uint2*)&At[r * LDA + A_FEA + k4] = v;
    }
    {
        const float bv[4] = {R.bond0.x, R.bond0.y, R.bond0.z, R.bond0.w};
#pragma unroll
        for (int e = 0; e < 4; ++e) {
            int le = tid * 4 + e;                    // < 1024
            unsigned r = (unsigned)le / 41u, j = (unsigned)le - r * 41u;
            At[r * LDA + 2 * A_FEA + j] = f2bf(bv[e]);
        }
    }
    if (tid < 72) {
        const float bv[4] = {R.bond1.x, R.bond1.y, R.bond1.z, R.bond1.w};
#pragma unroll
        for (int e = 0; e < 4; ++e) {
            int le = 1024 + tid * 4 + e;             // < 1312
            unsigned r = (unsigned)le / 41u, j = (unsigned)le - r * 41u;
            At[r * LDA + 2 * A_FEA + j] = f2bf(bv[e]);
        }
    }
}

// ---- pass A: double-buffered MFMA GEMM; BN1 stats (+ optional bf16 spill).
// R5 body (84 VGPR). Occupancy fix: VGPR 84 is in the 65-128 HW bucket ->
// 16 waves/CU = 4 blocks/CU schedulable (launch_bounds min != cap). Grid
// must SUPPLY them: 1024 blocks = 4/CU exactly, balanced 18/19-tile split.
// Spill layout (uint4): gated[t*512 + rt*256 + tid] = {F01,F23,C01,C23}.
template <bool STORE>
__global__ __launch_bounds__(256, 3)
void k_gemm_spill(const float* __restrict__ atom, const float* __restrict__ nbr,
                  const int* __restrict__ idx, const float* __restrict__ W,
                  float* __restrict__ stats, uint4* __restrict__ gated) {
    __shared__ __align__(16) unsigned short At[2][TR32 * LDA];   // 2 x 12800 B
    const int tid = threadIdx.x;
    for (int i = tid; i < 2 * TR32 * (KP - KF); i += 256) {      // zero K-pad
        int b  = i / (TR32 * (KP - KF));
        int ii = i - b * (TR32 * (KP - KF));
        int r  = ii / (KP - KF);
        int j  = KF + ii - r * (KP - KF);
        At[b][r * LDA + j] = 0;
    }
    const int lane = tid & 63, gg = tid >> 6;
    const int col  = lane & 15, q8 = (lane >> 4) * 8;
    const int r16  = tid >> 4;          // 0..15
    const int k4   = (tid & 15) * 4;

    s16x8 bfr[2][6];                    // 48 VGPRs of W fragments
#pragma unroll
    for (int tt = 0; tt < 2; ++tt) {
        const float* wr = W + ((gg + tt * 4) * 16 + col) * KF;
#pragma unroll
        for (int kc = 0; kc < 6; ++kc) {
            int kb = kc * 32 + q8;
            s16x8 f;
#pragma unroll
            for (int j = 0; j < 8; ++j) {
                int k = kb + j;
                f[j] = (short)f2bf(k < KF ? wr[k] : 0.f);
            }
            bfr[tt][kc] = f;
        }
    }

    // balanced split: base tiles each, first `rem` blocks get one extra
    const int base = NT32 / gridDim.x;
    const int rem  = NT32 % gridDim.x;
    const int bid  = blockIdx.x;
    const int tA   = bid * base + min(bid, rem);
    const int tB   = tA + base + (bid < rem ? 1 : 0);

    float s[2] = {0.f, 0.f}, q[2] = {0.f, 0.f};
    TileRegs R;
    int nbiN[2];
    if (tA < tB) {
        int rb = tA * TR32;
        int nbiC[2] = {idx[rb + r16], idx[rb + r16 + 16]};
        issue_selfbond(R, atom, nbr, rb, r16, k4, tid);
        issue_gat(R, atom, nbiC, k4);
        if (tA + 1 < tB) {
            int rb1 = rb + TR32;
            nbiN[0] = idx[rb1 + r16]; nbiN[1] = idx[rb1 + r16 + 16];
        }
    }
    int p = 0;
    for (int t = tA; t < tB; ++t) {
        write_tile(At[p], R, r16, k4, tid);       // waits (vmcnt) on tile-t loads
        if (t + 1 < tB) {                         // issue tile t+1 loads now
            issue_selfbond(R, atom, nbr, (t + 1) * TR32, r16, k4, tid);
            issue_gat(R, atom, nbiN, k4);         // idx prefetched 1 tile earlier
            if (t + 2 < tB) {
                int rb2 = (t + 2) * TR32;
                nbiN[0] = idx[rb2 + r16]; nbiN[1] = idx[rb2 + r16 + 16];
            }
        }
        BAR_LGKM();                               // drains ds only; t+1 loads stay in flight
        const unsigned short* A = At[p];
        f32x4 acc[2][2];
#pragma unroll
        for (int rt = 0; rt < 2; ++rt)
#pragma unroll
            for (int tt = 0; tt < 2; ++tt) acc[rt][tt] = (f32x4){0.f, 0.f, 0.f, 0.f};
#pragma unroll
        for (int kc = 0; kc < 6; ++kc) {
            const int k0 = kc * 32;
            const s16x8 a0 = *(const s16x8*)&A[(col) * LDA + k0 + q8];
            const s16x8 a1 = *(const s16x8*)&A[(16 + col) * LDA + k0 + q8];
#pragma unroll
            for (int tt = 0; tt < 2; ++tt) {
                acc[0][tt] = __builtin_amdgcn_mfma_f32_16x16x32_bf16(a0, bfr[tt][kc], acc[0][tt], 0, 0, 0);
                acc[1][tt] = __builtin_amdgcn_mfma_f32_16x16x32_bf16(a1, bfr[tt][kc], acc[1][tt], 0, 0, 0);
            }
        }
#pragma unroll
        for (int tt = 0; tt < 2; ++tt)
#pragma unroll
            for (int rt = 0; rt < 2; ++rt)
#pragma unroll
                for (int e = 0; e < 4; ++e) {
                    float v = acc[rt][tt][e];
                    s[tt] += v; q[tt] = fmaf(v, v, q[tt]);
                }
        if (STORE) {
#pragma unroll
            for (int rt = 0; rt < 2; ++rt) {
                uint4 u;
                u.x = pack2bf(acc[rt][0][0], acc[rt][0][1]);
                u.y = pack2bf(acc[rt][0][2], acc[rt][0][3]);
                u.z = pack2bf(acc[rt][1][0], acc[rt][1][1]);
                u.w = pack2bf(acc[rt][1][2], acc[rt][1][3]);
                gated[(size_t)t * 512 + rt * 256 + tid] = u;
            }
        }
        p ^= 1;
        // single barrier/iter safe: buf[p] rewritten at iter t+2, after
        // barrier(t+1); lgkmcnt(0) there drains buf[p] ds_reads from iter t.
    }
#pragma unroll
    for (int tt = 0; tt < 2; ++tt) {
        float sv = s[tt], qv = q[tt];
        sv += __shfl_xor(sv, 16); sv += __shfl_xor(sv, 32);
        qv += __shfl_xor(qv, 16); qv += __shfl_xor(qv, 32);
        if (lane < 16) {
            int c = (gg + tt * 4) * 16 + col;
            atomicAdd(&stats[WS_SUM1 + c], sv);
            atomicAdd(&stats[WS_SUMSQ1 + c], qv);
        }
    }
}

// ---- pass B: stream gated bf16; BN1 + sigmoid*softplus; m-sum over 192-row
// (16-atom) tiles via plain LDS + per-thread 12-row sums; BN2 stats inline.
// Loads for T+grid issued AFTER compute (single-buffer G reuse, no double
// liveness); they fly across barrier(2) + reduce + barrier(1) to first use.
__global__ __launch_bounds__(256, 3)
void k_apply(const uint4* __restrict__ gated,
             const float* __restrict__ g1, const float* __restrict__ b1,
             float* __restrict__ stats, float* __restrict__ dout) {
    __shared__ float S2[192 * S2S];   // 52224 B -> 3 blocks/CU (LDS cap)
    const int tid = threadIdx.x, lane = tid & 63;
    const int col = lane & 15, quad = lane >> 4, gg = tid >> 6;
    const int cF = gg * 16 + col, cC = cF + 64;

    const float invn = 1.f / (float)NROW;
    float meanF = stats[WS_SUM1 + cF] * invn;
    float varF  = stats[WS_SUMSQ1 + cF] * invn - meanF * meanF;
    float scF   = g1[cF] * rsqrtf(varF + BN_EPS), shF = b1[cF] - meanF * scF;
    float meanC = stats[WS_SUM1 + cC] * invn;
    float varC  = stats[WS_SUMSQ1 + cC] * invn - meanC * meanC;
    float scC   = g1[cC] * rsqrtf(varC + BN_EPS), shC = b1[cC] - meanC * scC;

    uint4 G[6][2];
    if (blockIdx.x < NT192) {          // prologue loads for T0
#pragma unroll
        for (int sub = 0; sub < 6; ++sub) {
            const size_t base = (size_t)(blockIdx.x * 6 + sub) * 512 + tid;
#pragma unroll
            for (int rt = 0; rt < 2; ++rt) G[sub][rt] = gated[base + rt * 256];
        }
    }

    float bs = 0.f, bq = 0.f;
    for (int T = blockIdx.x; T < NT192; T += gridDim.x) {
        BAR_LGKM();                    // previous reduce reads done; G loads in flight
#pragma unroll
        for (int sub = 0; sub < 6; ++sub)
#pragma unroll
            for (int rt = 0; rt < 2; ++rt) {
                const uint4 u = G[sub][rt];      // first use waits vmcnt here
                const float fv[4] = {bf_lo(u.x), bf_hi(u.x), bf_lo(u.y), bf_hi(u.y)};
                const float cv[4] = {bf_lo(u.z), bf_hi(u.z), bf_lo(u.w), bf_hi(u.w)};
#pragma unroll
                for (int e = 0; e < 4; ++e) {
                    float gF = fmaf(fv[e], scF, shF);
                    float gC = fmaf(cv[e], scC, shC);
                    float v  = fsigmoid(gF) * fsoftplus(gC);
                    int row = sub * 32 + rt * 16 + quad * 4 + e;
                    S2[row * S2S + cF] = v;    // unique (row, c) writer
                }
            }
        __builtin_amdgcn_sched_barrier(0);      // keep reloads BELOW last G use
        const int Tn = T + gridDim.x;
        if (Tn < NT192) {              // refill G for next tile (regs now dead)
#pragma unroll
            for (int sub = 0; sub < 6; ++sub) {
                const size_t base = (size_t)(Tn * 6 + sub) * 512 + tid;
#pragma unroll
                for (int rt = 0; rt < 2; ++rt) G[sub][rt] = gated[base + rt * 256];
            }
        }
        BAR_LGKM();                    // S2 writes visible; new G loads in flight
#pragma unroll
        for (int j = 0; j < 4; ++j) {
            int lin = tid + j * 256;
            int a = lin >> 6, c = lin & 63;
            const float* pp = &S2[(a * 12) * S2S + c];
            float sum = 0.f;
#pragma unroll
            for (int m = 0; m < 12; ++m) sum += pp[m * S2S];
            dout[((size_t)T * 16 + a) * 64 + c] = sum;
            bs += sum; bq = fmaf(sum, sum, bq);
        }
    }
    BAR_LGKM();
    S2[tid] = bs; S2[256 + tid] = bq;
    __syncthreads();
    if (tid < 64) {
        float ss = S2[tid] + S2[tid + 64] + S2[tid + 128] + S2[tid + 192];
        float qq = S2[256 + tid] + S2[256 + tid + 64] + S2[256 + tid + 128] + S2[256 + tid + 192];
        atomicAdd(&stats[WS_SUM2 + tid], ss);
        atomicAdd(&stats[WS_SUMSQ2 + tid], qq);
    }
}

// ---- fallback main (ws too small): same GEMM structure, atomic epilogue.
__global__ __launch_bounds__(256, 2)
void k_gemm_main(const float* __restrict__ atom, const float* __restrict__ nbr,
                 const int* __restrict__ idx, const float* __restrict__ W,
                 const float* __restrict__ g1, const float* __restrict__ b1,
                 const float* __restrict__ stats, float* __restrict__ dout) {
    __shared__ __align__(16) unsigned short At[TR32 * LDA];
    __shared__ float S[4 * 64];       // <=4 atoms per 32-row tile
    const int tid = threadIdx.x;
    for (int i = tid; i < TR32 * (KP - KF); i += 256) {
        int r = i / (KP - KF), j = KF + i - r * (KP - KF);
        At[r * LDA + j] = 0;
    }
    for (int i = tid; i < 4 * 64; i += 256) S[i] = 0.f;
    const int lane = tid & 63, gg = tid >> 6;
    const int col = lane & 15, q8 = (lane >> 4) * 8, quad = lane >> 4;
    const int r16 = tid >> 4, k4 = (tid & 15) * 4;

    s16x8 bfr[2][6];
#pragma unroll
    for (int tt = 0; tt < 2; ++tt) {
        const float* wr = W + ((gg + tt * 4) * 16 + col) * KF;
#pragma unroll
        for (int kc = 0; kc < 6; ++kc) {
            int kb = kc * 32 + q8;
            s16x8 f;
#pragma unroll
            for (int j = 0; j < 8; ++j) { int k = kb + j; f[j] = (short)f2bf(k < KF ? wr[k] : 0.f); }
            bfr[tt][kc] = f;
        }
    }
    const float invn = 1.f / (float)NROW;
    float sc[2], sh[2];
#pragma unroll
    for (int tt = 0; tt < 2; ++tt) {
        int c = (gg + tt * 4) * 16 + col;
        float mean = stats[WS_SUM1 + c] * invn;
        float var  = stats[WS_SUMSQ1 + c] * invn - mean * mean;
        sc[tt] = g1[c] * rsqrtf(var + BN_EPS);
        sh[tt] = b1[c] - mean * sc[tt];
    }
    const int per = (NT32 + gridDim.x - 1) / gridDim.x;
    const int tA = blockIdx.x * per, tB = min(NT32, tA + per);
    for (int t = tA; t < tB; ++t) {
        const int rb = t * TR32;
        __syncthreads();
        {
            TileRegs R;
            int nbiC[2] = {idx[rb + r16], idx[rb + r16 + 16]};
            issue_selfbond(R, atom, nbr, rb, r16, k4, tid);
            issue_gat(R, atom, nbiC, k4);
            write_tile(At, R, r16, k4, tid);
        }
        __syncthreads();
        f32x4 acc[2][2];
#pragma unroll
        for (int rt = 0; rt < 2; ++rt)
#pragma unroll
            for (int tt = 0; tt < 2; ++tt) acc[rt][tt] = (f32x4){0.f, 0.f, 0.f, 0.f};
#pragma unroll
        for (int kc = 0; kc < 6; ++kc) {
            const int k0 = kc * 32;
            const s16x8 a0 = *(const s16x8*)&At[(col) * LDA + k0 + q8];
            const s16x8 a1 = *(const s16x8*)&At[(16 + col) * LDA + k0 + q8];
#pragma unroll
            for (int tt = 0; tt < 2; ++tt) {
                acc[0][tt] = __builtin_amdgcn_mfma_f32_16x16x32_bf16(a0, bfr[tt][kc], acc[0][tt], 0, 0, 0);
                acc[1][tt] = __builtin_amdgcn_mfma_f32_16x16x32_bf16(a1, bfr[tt][kc], acc[1][tt], 0, 0, 0);
            }
        }
        const int a0i = rb / M_NBR;
#pragma unroll
        for (int rt = 0; rt < 2; ++rt)
#pragma unroll
            for (int e = 0; e < 4; ++e) {
                float gF = fmaf(acc[rt][0][e], sc[0], sh[0]);
                float gC = fmaf(acc[rt][1][e], sc[1], sh[1]);
                float v  = fsigmoid(gF) * fsoftplus(gC);
                int row = rb + rt * 16 + quad * 4 + e;
                atomicAdd(&S[(row / M_NBR - a0i) * 64 + gg * 16 + col], v);
            }
        __syncthreads();
        const int amax = (rb + TR32 - 1) / M_NBR - a0i;
        for (int i = tid; i < 4 * 64; i += 256) {
            float v = S[i];
            S[i] = 0.f;
            int a = i >> 6;
            if (a <= amax) atomicAdd(&dout[(a0i + a) * 64 + (i & 63)], v);
        }
    }
}

__global__ __launch_bounds__(256, 1)
void k_bn2_stats(const float* __restrict__ dout, float* __restrict__ stats) {
    int tid = threadIdx.x;
    int c = tid & 63;
    int g = tid >> 6;
    float s = 0.f, q = 0.f;
    for (int n = blockIdx.x * 4 + g; n < N_ATOMS; n += gridDim.x * 4) {
        float v = dout[n * 64 + c];
        s += v; q = fmaf(v, v, q);
    }
    __shared__ float red[4][64];
    red[g][c] = s;
    __syncthreads();
    if (g == 0)
        atomicAdd(&stats[WS_SUM2 + c], red[0][c] + red[1][c] + red[2][c] + red[3][c]);
    __syncthreads();
    red[g][c] = q;
    __syncthreads();
    if (g == 0)
        atomicAdd(&stats[WS_SUMSQ2 + c], red[0][c] + red[1][c] + red[2][c] + red[3][c]);
}

__global__ void k_final(const float* __restrict__ atom, const float* __restrict__ g2,
                        const float* __restrict__ b2, const float* __restrict__ stats,
                        float* __restrict__ dout) {
    int i0 = blockIdx.x * blockDim.x + threadIdx.x;
    int c = i0 & 63;
    const float invn = 1.f / (float)N_ATOMS;
    float mean = stats[WS_SUM2 + c] * invn;
    float var  = stats[WS_SUMSQ2 + c] * invn - mean * mean;
    float sc   = g2[c] * rsqrtf(var + BN_EPS);
    float sh   = b2[c] - mean * sc;
    int stride = gridDim.x * blockDim.x;
    for (int i = i0; i < N_ATOMS * A_FEA; i += stride) {
        float v = fmaf(dout[i], sc, sh) + atom[i];
        dout[i] = fsoftplus(v);
    }
}

extern "C" void kernel_launch(void* const* d_in, const int* in_sizes, int n_in,
                              void* d_out, int out_size, void* d_ws, size_t ws_size,
                              hipStream_t stream) {
    const float* atom = (const float*)d_in[0];
    const float* nbr  = (const float*)d_in[1];
    const int*   idx  = (const int*)d_in[2];
    const float* W    = (const float*)d_in[3];
    // d_in[4] (bias b) is mathematically absorbed by BN1 -> unused
    const float* g1   = (const float*)d_in[5];
    const float* b1   = (const float*)d_in[6];
    const float* g2   = (const float*)d_in[7];
    const float* b2   = (const float*)d_in[8];
    float* dout  = (float*)d_out;
    float* stats = (float*)d_ws;
    uint4* gated = (uint4*)((char*)d_ws + WS_GATED_OFF);

    const bool fused = ws_size >= (WS_GATED_OFF + GATED_BYTES);

    if (fused) {
        k_zero_stats<<<2, 256, 0, stream>>>(stats);
        // grid 1024 = 4 blocks/CU x 256 CU (VGPR-84 bucket allows 16 waves/CU);
        // balanced 18/19-tile split inside the kernel.
        k_gemm_spill<true><<<1024, 256, 0, stream>>>(atom, nbr, idx, W, stats, gated);
        // grid 768 = 3 blocks/CU (LDS cap); grid-stride over 3125 tiles.
        k_apply<<<768, 256, 0, stream>>>(gated, g1, b1, stats, dout);
        k_final<<<512, 256, 0, stream>>>(atom, g2, b2, stats, dout);
    } else {
        k_zero<<<512, 256, 0, stream>>>(dout, stats);
        k_gemm_spill<false><<<1024, 256, 0, stream>>>(atom, nbr, idx, W, stats, nullptr);
        k_gemm_main<<<1024, 256, 0, stream>>>(atom, nbr, idx, W, g1, b1, stats, dout);
        k_bn2_stats<<<256, 256, 0, stream>>>(dout, stats);
        k_final<<<512, 256, 0, stream>>>(atom, g2, b2, stats, dout);
    }
}

// Round 9
// 255.783 us; speedup vs baseline: 1.0546x; 1.0546x over previous
//
#include <hip/hip_runtime.h>
#include <math.h>

#define N_ATOMS 50000
#define M_NBR   12
#define A_FEA   64
#define B_FEA   41
#define KF      169      // 2*A + B
#define KP      192      // padded K (6 chunks of 32)
#define LDA     200      // LDS row stride in bf16 (400 B -> free 2-way banking)
#define OC      128      // 2*A
#define NROW    600000   // N_ATOMS * M_NBR
#define TR32    32       // rows per GEMM tile
#define NT32    18750    // NROW / 32
#define NT192   3125     // NROW / 192 (16-atom apply tiles)
#define BN_EPS  1e-5f
#define L2E     1.44269504088896340736f
#define LN2     0.693147180559945309417f

// d_ws layout
#define WS_SUM1   0
#define WS_SUMSQ1 128
#define WS_SUM2   256
#define WS_SUMSQ2 320
#define WS_NFLOAT 384
#define WS_GATED_OFF 2048ull
#define GATED_BYTES  ((size_t)NT32 * 512 * 16)   // 153.6 MB of bf16 (uint4 layout)

// Workgroup barrier draining ONLY lgkmcnt (R5: null vs __syncthreads, kept).
#define BAR_LGKM() asm volatile("s_waitcnt lgkmcnt(0)\n\ts_barrier" ::: "memory")

typedef __attribute__((ext_vector_type(8))) short s16x8;
typedef __attribute__((ext_vector_type(4))) float f32x4;

__device__ __forceinline__ float fsigmoid(float x) {
    float e = __builtin_amdgcn_exp2f(-x * L2E);
    return __builtin_amdgcn_rcpf(1.f + e);
}
__device__ __forceinline__ float fsoftplus(float x) {
    float e = __builtin_amdgcn_exp2f(-fabsf(x) * L2E);
    return fmaxf(x, 0.f) + __builtin_amdgcn_logf(1.f + e) * LN2;
}
__device__ __forceinline__ unsigned short f2bf(float f) {
    unsigned int u = __float_as_uint(f);
    u += 0x7FFFu + ((u >> 16) & 1u);     // RNE
    return (unsigned short)(u >> 16);
}
__device__ __forceinline__ unsigned int pack2bf(float lo, float hi) {
    return (unsigned int)f2bf(lo) | ((unsigned int)f2bf(hi) << 16);
}
__device__ __forceinline__ float bf_lo(unsigned int u) { return __uint_as_float(u << 16); }
__device__ __forceinline__ float bf_hi(unsigned int u) { return __uint_as_float(u & 0xFFFF0000u); }

__global__ void k_zero_stats(float* __restrict__ stats) {
    int i = blockIdx.x * blockDim.x + threadIdx.x;
    if (i < WS_NFLOAT) stats[i] = 0.f;
}
__global__ void k_zero(float* __restrict__ dout, float* __restrict__ stats) {
    int i = blockIdx.x * blockDim.x + threadIdx.x;
    int stride = gridDim.x * blockDim.x;
    for (int j = i; j < N_ATOMS * A_FEA; j += stride) dout[j] = 0.f;
    if (i < WS_NFLOAT) stats[i] = 0.f;
}

// ---- register staging state for one 32-row tile ----------------------------
struct TileRegs {
    float4 selfv[2];
    float4 gat[2];
    float4 bond0, bond1;
};

__device__ __forceinline__ void issue_selfbond(TileRegs& R, const float* __restrict__ atom,
                                               const float* __restrict__ nbr,
                                               int rb, int r16, int k4, int tid) {
#pragma unroll
    for (int it = 0; it < 2; ++it) {
        int row = rb + r16 + it * 16;
        R.selfv[it] = *(const float4*)(atom + ((unsigned)row / 12u) * A_FEA + k4);
    }
    const float* bb = nbr + (size_t)rb * B_FEA;   // 1312 floats = 328 float4, 16B-aligned
    R.bond0 = *(const float4*)(bb + (size_t)tid * 4);
    if (tid < 72) R.bond1 = *(const float4*)(bb + (size_t)(256 + tid) * 4);
}
__device__ __forceinline__ void issue_gat(TileRegs& R, const float* __restrict__ atom,
                                          const int nbi[2], int k4) {
#pragma unroll
    for (int it = 0; it < 2; ++it)
        R.gat[it] = *(const float4*)(atom + (unsigned)nbi[it] * A_FEA + k4);
}
__device__ __forceinline__ void write_tile(unsigned short* __restrict__ At,
                                           const TileRegs& R, int r16, int k4, int tid) {
#pragma unroll
    for (int it = 0; it < 2; ++it) {
        int r = r16 + it * 16;
        uint2 u;
        u.x = pack2bf(R.selfv[it].x, R.selfv[it].y);
        u.y = pack2bf(R.selfv[it].z, R.selfv[it].w);
        *(uint2*)&At[r * LDA + k4] = u;
        uint2 v;
        v.x = pack2bf(R.gat[it].x, R.gat[it].y);
        v.y = pack2bf(R.gat[it].z, R.gat[it].w);
        *(uint2*)&At[r * LDA + A_FEA + k4] = v;
    }
    {
        const float bv[4] = {R.bond0.x, R.bond0.y, R.bond0.z, R.bond0.w};
#pragma unroll
        for (int e = 0; e < 4; ++e) {
            int le = tid * 4 + e;                    // < 1024
            unsigned r = (unsigned)le / 41u, j = (unsigned)le - r * 41u;
            At[r * LDA + 2 * A_FEA + j] = f2bf(bv[e]);
        }
    }
    if (tid < 72) {
        const float bv[4] = {R.bond1.x, R.bond1.y, R.bond1.z, R.bond1.w};
#pragma unroll
        for (int e = 0; e < 4; ++e) {
            int le = 1024 + tid * 4 + e;             // < 1312
            unsigned r = (unsigned)le / 41u, j = (unsigned)le - r * 41u;
            At[r * LDA + 2 * A_FEA + j] = f2bf(bv[e]);
        }
    }
}

// ---- pass A: double-buffered MFMA GEMM; BN1 stats (+ optional bf16 spill).
// R5 configuration (best measured: 86.4 us): grid 750 = 25 tiles/block,
// 3 blocks/CU, 84 VGPR. R3 (2-deep ILP), R4 (5 blk/CU), R6 (grid 1024) all
// regressed -> this is the structure's local optimum; do not re-perturb.
// Spill layout (uint4): gated[t*512 + rt*256 + tid] = {F01,F23,C01,C23},
// i.e. one uint4 = 4 consecutive rows (quad*4+e) of channel gg*16+col (F)
// and channel +64 (C).
template <bool STORE>
__global__ __launch_bounds__(256, 3)
void k_gemm_spill(const float* __restrict__ atom, const float* __restrict__ nbr,
                  const int* __restrict__ idx, const float* __restrict__ W,
                  float* __restrict__ stats, uint4* __restrict__ gated) {
    __shared__ __align__(16) unsigned short At[2][TR32 * LDA];   // 2 x 12800 B
    const int tid = threadIdx.x;
    for (int i = tid; i < 2 * TR32 * (KP - KF); i += 256) {      // zero K-pad
        int b  = i / (TR32 * (KP - KF));
        int ii = i - b * (TR32 * (KP - KF));
        int r  = ii / (KP - KF);
        int j  = KF + ii - r * (KP - KF);
        At[b][r * LDA + j] = 0;
    }
    const int lane = tid & 63, gg = tid >> 6;
    const int col  = lane & 15, q8 = (lane >> 4) * 8;
    const int r16  = tid >> 4;          // 0..15
    const int k4   = (tid & 15) * 4;

    s16x8 bfr[2][6];                    // 48 VGPRs of W fragments
#pragma unroll
    for (int tt = 0; tt < 2; ++tt) {
        const float* wr = W + ((gg + tt * 4) * 16 + col) * KF;
#pragma unroll
        for (int kc = 0; kc < 6; ++kc) {
            int kb = kc * 32 + q8;
            s16x8 f;
#pragma unroll
            for (int j = 0; j < 8; ++j) {
                int k = kb + j;
                f[j] = (short)f2bf(k < KF ? wr[k] : 0.f);
            }
            bfr[tt][kc] = f;
        }
    }

    // balanced split (degenerates to exact 25/block at grid 750)
    const int base = NT32 / gridDim.x;
    const int rem  = NT32 % gridDim.x;
    const int bid  = blockIdx.x;
    const int tA   = bid * base + min(bid, rem);
    const int tB   = tA + base + (bid < rem ? 1 : 0);

    float s[2] = {0.f, 0.f}, q[2] = {0.f, 0.f};
    TileRegs R;
    int nbiN[2];
    if (tA < tB) {
        int rb = tA * TR32;
        int nbiC[2] = {idx[rb + r16], idx[rb + r16 + 16]};
        issue_selfbond(R, atom, nbr, rb, r16, k4, tid);
        issue_gat(R, atom, nbiC, k4);
        if (tA + 1 < tB) {
            int rb1 = rb + TR32;
            nbiN[0] = idx[rb1 + r16]; nbiN[1] = idx[rb1 + r16 + 16];
        }
    }
    int p = 0;
    for (int t = tA; t < tB; ++t) {
        write_tile(At[p], R, r16, k4, tid);       // waits (vmcnt) on tile-t loads
        if (t + 1 < tB) {                         // issue tile t+1 loads now
            issue_selfbond(R, atom, nbr, (t + 1) * TR32, r16, k4, tid);
            issue_gat(R, atom, nbiN, k4);         // idx prefetched 1 tile earlier
            if (t + 2 < tB) {
                int rb2 = (t + 2) * TR32;
                nbiN[0] = idx[rb2 + r16]; nbiN[1] = idx[rb2 + r16 + 16];
            }
        }
        BAR_LGKM();                               // drains ds only; t+1 loads in flight
        const unsigned short* A = At[p];
        f32x4 acc[2][2];
#pragma unroll
        for (int rt = 0; rt < 2; ++rt)
#pragma unroll
            for (int tt = 0; tt < 2; ++tt) acc[rt][tt] = (f32x4){0.f, 0.f, 0.f, 0.f};
#pragma unroll
        for (int kc = 0; kc < 6; ++kc) {
            const int k0 = kc * 32;
            const s16x8 a0 = *(const s16x8*)&A[(col) * LDA + k0 + q8];
            const s16x8 a1 = *(const s16x8*)&A[(16 + col) * LDA + k0 + q8];
#pragma unroll
            for (int tt = 0; tt < 2; ++tt) {
                acc[0][tt] = __builtin_amdgcn_mfma_f32_16x16x32_bf16(a0, bfr[tt][kc], acc[0][tt], 0, 0, 0);
                acc[1][tt] = __builtin_amdgcn_mfma_f32_16x16x32_bf16(a1, bfr[tt][kc], acc[1][tt], 0, 0, 0);
            }
        }
#pragma unroll
        for (int tt = 0; tt < 2; ++tt)
#pragma unroll
            for (int rt = 0; rt < 2; ++rt)
#pragma unroll
                for (int e = 0; e < 4; ++e) {
                    float v = acc[rt][tt][e];
                    s[tt] += v; q[tt] = fmaf(v, v, q[tt]);
                }
        if (STORE) {
#pragma unroll
            for (int rt = 0; rt < 2; ++rt) {
                uint4 u;
                u.x = pack2bf(acc[rt][0][0], acc[rt][0][1]);
                u.y = pack2bf(acc[rt][0][2], acc[rt][0][3]);
                u.z = pack2bf(acc[rt][1][0], acc[rt][1][1]);
                u.w = pack2bf(acc[rt][1][2], acc[rt][1][3]);
                gated[(size_t)t * 512 + rt * 256 + tid] = u;
            }
        }
        p ^= 1;
        // single barrier/iter safe: buf[p] rewritten at iter t+2, after
        // barrier(t+1); lgkmcnt(0) there drains buf[p] ds_reads from iter t.
    }
#pragma unroll
    for (int tt = 0; tt < 2; ++tt) {
        float sv = s[tt], qv = q[tt];
        sv += __shfl_xor(sv, 16); sv += __shfl_xor(sv, 32);
        qv += __shfl_xor(qv, 16); qv += __shfl_xor(qv, 32);
        if (lane < 16) {
            int c = (gg + tt * 4) * 16 + col;
            atomicAdd(&stats[WS_SUM1 + c], sv);
            atomicAdd(&stats[WS_SUMSQ1 + c], qv);
        }
    }
}

// ---- pass B: stream gated bf16; BN1 + sigmoid*softplus + m-sum + BN2 stats.
// BARRIER-FREE: one uint4 of the spill = 4 consecutive rows of one (F,C)
// channel pair; an atom's 12 rows = exactly 3 consecutive uint4 row-groups.
// Thread (wave w, lane c) owns (atom j*4+w, channel c): reads its 3 uint4s
// per atom, reduces 12 rows IN REGISTERS, writes one dout value. No LDS
// tile, no per-tile barriers, no cross-lane ops. Static G indexing (rule
// #20 safe). LDS 2 KB.
__global__ __launch_bounds__(256, 3)
void k_apply(const uint4* __restrict__ gated,
             const float* __restrict__ g1, const float* __restrict__ b1,
             float* __restrict__ stats, float* __restrict__ dout) {
    __shared__ float red[512];
    const int tid = threadIdx.x;
    const int c   = tid & 63;          // channel 0..63 (filter; core = c+64)
    const int w   = tid >> 6;          // wave id 0..3 -> atom sub-block
    const int col = c & 15, gg = c >> 4;

    const float invn = 1.f / (float)NROW;
    float meanF = stats[WS_SUM1 + c] * invn;
    float varF  = stats[WS_SUMSQ1 + c] * invn - meanF * meanF;
    float scF   = g1[c] * rsqrtf(varF + BN_EPS), shF = b1[c] - meanF * scF;
    const int cc = c + 64;
    float meanC = stats[WS_SUM1 + cc] * invn;
    float varC  = stats[WS_SUMSQ1 + cc] * invn - meanC * meanC;
    float scC   = g1[cc] * rsqrtf(varC + BN_EPS), shC = b1[cc] - meanC * scC;

    float bs = 0.f, bq = 0.f;
    for (int T = blockIdx.x; T < NT192; T += gridDim.x) {
        uint4 G[4][3];                 // batch all 12 loads (48 VGPR, static idx)
#pragma unroll
        for (int j = 0; j < 4; ++j) {
            const int a = j * 4 + w;   // atom within tile 0..15
#pragma unroll
            for (int l = 0; l < 3; ++l) {
                const int Gi  = 3 * a + l;          // row-group 0..47
                const int sub = Gi >> 3, rt = (Gi >> 2) & 1, q = Gi & 3;
                G[j][l] = gated[(size_t)(T * 6 + sub) * 512 + rt * 256
                                + gg * 64 + q * 16 + col];
            }
        }
#pragma unroll
        for (int j = 0; j < 4; ++j) {
            float sum = 0.f;
#pragma unroll
            for (int l = 0; l < 3; ++l) {
                const uint4 u = G[j][l];
                const float fv[4] = {bf_lo(u.x), bf_hi(u.x), bf_lo(u.y), bf_hi(u.y)};
                const float cv[4] = {bf_lo(u.z), bf_hi(u.z), bf_lo(u.w), bf_hi(u.w)};
#pragma unroll
                for (int e = 0; e < 4; ++e) {
                    float gF = fmaf(fv[e], scF, shF);
                    float gC = fmaf(cv[e], scC, shC);
                    sum += fsigmoid(gF) * fsoftplus(gC);
                }
            }
            const int a = j * 4 + w;
            dout[((size_t)T * 16 + a) * 64 + c] = sum;
            bs += sum; bq = fmaf(sum, sum, bq);
        }
    }
    red[tid] = bs; red[256 + tid] = bq;
    __syncthreads();
    if (tid < 64) {
        float ss = red[tid] + red[tid + 64] + red[tid + 128] + red[tid + 192];
        float qq = red[256 + tid] + red[256 + tid + 64] + red[256 + tid + 128] + red[256 + tid + 192];
        atomicAdd(&stats[WS_SUM2 + tid], ss);
        atomicAdd(&stats[WS_SUMSQ2 + tid], qq);
    }
}

// ---- fallback main (ws too small): same GEMM structure, atomic epilogue.
__global__ __launch_bounds__(256, 2)
void k_gemm_main(const float* __restrict__ atom, const float* __restrict__ nbr,
                 const int* __restrict__ idx, const float* __restrict__ W,
                 const float* __restrict__ g1, const float* __restrict__ b1,
                 const float* __restrict__ stats, float* __restrict__ dout) {
    __shared__ __align__(16) unsigned short At[TR32 * LDA];
    __shared__ float S[4 * 64];       // <=4 atoms per 32-row tile
    const int tid = threadIdx.x;
    for (int i = tid; i < TR32 * (KP - KF); i += 256) {
        int r = i / (KP - KF), j = KF + i - r * (KP - KF);
        At[r * LDA + j] = 0;
    }
    for (int i = tid; i < 4 * 64; i += 256) S[i] = 0.f;
    const int lane = tid & 63, gg = tid >> 6;
    const int col = lane & 15, q8 = (lane >> 4) * 8, quad = lane >> 4;
    const int r16 = tid >> 4, k4 = (tid & 15) * 4;

    s16x8 bfr[2][6];
#pragma unroll
    for (int tt = 0; tt < 2; ++tt) {
        const float* wr = W + ((gg + tt * 4) * 16 + col) * KF;
#pragma unroll
        for (int kc = 0; kc < 6; ++kc) {
            int kb = kc * 32 + q8;
            s16x8 f;
#pragma unroll
            for (int j = 0; j < 8; ++j) { int k = kb + j; f[j] = (short)f2bf(k < KF ? wr[k] : 0.f); }
            bfr[tt][kc] = f;
        }
    }
    const float invn = 1.f / (float)NROW;
    float sc[2], sh[2];
#pragma unroll
    for (int tt = 0; tt < 2; ++tt) {
        int c = (gg + tt * 4) * 16 + col;
        float mean = stats[WS_SUM1 + c] * invn;
        float var  = stats[WS_SUMSQ1 + c] * invn - mean * mean;
        sc[tt] = g1[c] * rsqrtf(var + BN_EPS);
        sh[tt] = b1[c] - mean * sc[tt];
    }
    const int per = (NT32 + gridDim.x - 1) / gridDim.x;
    const int tA = blockIdx.x * per, tB = min(NT32, tA + per);
    for (int t = tA; t < tB; ++t) {
        const int rb = t * TR32;
        __syncthreads();
        {
            TileRegs R;
            int nbiC[2] = {idx[rb + r16], idx[rb + r16 + 16]};
            issue_selfbond(R, atom, nbr, rb, r16, k4, tid);
            issue_gat(R, atom, nbiC, k4);
            write_tile(At, R, r16, k4, tid);
        }
        __syncthreads();
        f32x4 acc[2][2];
#pragma unroll
        for (int rt = 0; rt < 2; ++rt)
#pragma unroll
            for (int tt = 0; tt < 2; ++tt) acc[rt][tt] = (f32x4){0.f, 0.f, 0.f, 0.f};
#pragma unroll
        for (int kc = 0; kc < 6; ++kc) {
            const int k0 = kc * 32;
            const s16x8 a0 = *(const s16x8*)&At[(col) * LDA + k0 + q8];
            const s16x8 a1 = *(const s16x8*)&At[(16 + col) * LDA + k0 + q8];
#pragma unroll
            for (int tt = 0; tt < 2; ++tt) {
                acc[0][tt] = __builtin_amdgcn_mfma_f32_16x16x32_bf16(a0, bfr[tt][kc], acc[0][tt], 0, 0, 0);
                acc[1][tt] = __builtin_amdgcn_mfma_f32_16x16x32_bf16(a1, bfr[tt][kc], acc[1][tt], 0, 0, 0);
            }
        }
        const int a0i = rb / M_NBR;
#pragma unroll
        for (int rt = 0; rt < 2; ++rt)
#pragma unroll
            for (int e = 0; e < 4; ++e) {
                float gF = fmaf(acc[rt][0][e], sc[0], sh[0]);
                float gC = fmaf(acc[rt][1][e], sc[1], sh[1]);
                float v  = fsigmoid(gF) * fsoftplus(gC);
                int row = rb + rt * 16 + quad * 4 + e;
                atomicAdd(&S[(row / M_NBR - a0i) * 64 + gg * 16 + col], v);
            }
        __syncthreads();
        const int amax = (rb + TR32 - 1) / M_NBR - a0i;
        for (int i = tid; i < 4 * 64; i += 256) {
            float v = S[i];
            S[i] = 0.f;
            int a = i >> 6;
            if (a <= amax) atomicAdd(&dout[(a0i + a) * 64 + (i & 63)], v);
        }
    }
}

__global__ __launch_bounds__(256, 1)
void k_bn2_stats(const float* __restrict__ dout, float* __restrict__ stats) {
    int tid = threadIdx.x;
    int c = tid & 63;
    int g = tid >> 6;
    float s = 0.f, q = 0.f;
    for (int n = blockIdx.x * 4 + g; n < N_ATOMS; n += gridDim.x * 4) {
        float v = dout[n * 64 + c];
        s += v; q = fmaf(v, v, q);
    }
    __shared__ float red[4][64];
    red[g][c] = s;
    __syncthreads();
    if (g == 0)
        atomicAdd(&stats[WS_SUM2 + c], red[0][c] + red[1][c] + red[2][c] + red[3][c]);
    __syncthreads();
    red[g][c] = q;
    __syncthreads();
    if (g == 0)
        atomicAdd(&stats[WS_SUMSQ2 + c], red[0][c] + red[1][c] + red[2][c] + red[3][c]);
}

__global__ void k_final(const float* __restrict__ atom, const float* __restrict__ g2,
                        const float* __restrict__ b2, const float* __restrict__ stats,
                        float* __restrict__ dout) {
    int i0 = blockIdx.x * blockDim.x + threadIdx.x;
    int c = i0 & 63;
    const float invn = 1.f / (float)N_ATOMS;
    float mean = stats[WS_SUM2 + c] * invn;
    float var  = stats[WS_SUMSQ2 + c] * invn - mean * mean;
    float sc   = g2[c] * rsqrtf(var + BN_EPS);
    float sh   = b2[c] - mean * sc;
    int stride = gridDim.x * blockDim.x;
    for (int i = i0; i < N_ATOMS * A_FEA; i += stride) {
        float v = fmaf(dout[i], sc, sh) + atom[i];
        dout[i] = fsoftplus(v);
    }
}

extern "C" void kernel_launch(void* const* d_in, const int* in_sizes, int n_in,
                              void* d_out, int out_size, void* d_ws, size_t ws_size,
                              hipStream_t stream) {
    const float* atom = (const float*)d_in[0];
    const float* nbr  = (const float*)d_in[1];
    const int*   idx  = (const int*)d_in[2];
    const float* W    = (const float*)d_in[3];
    // d_in[4] (bias b) is mathematically absorbed by BN1 -> unused
    const float* g1   = (const float*)d_in[5];
    const float* b1   = (const float*)d_in[6];
    const float* g2   = (const float*)d_in[7];
    const float* b2   = (const float*)d_in[8];
    float* dout  = (float*)d_out;
    float* stats = (float*)d_ws;
    uint4* gated = (uint4*)((char*)d_ws + WS_GATED_OFF);

    const bool fused = ws_size >= (WS_GATED_OFF + GATED_BYTES);

    if (fused) {
        k_zero_stats<<<2, 256, 0, stream>>>(stats);
        // grid 750: 25 tiles/block exact, 3 blocks/CU - best measured (R5).
        k_gemm_spill<true><<<750, 256, 0, stream>>>(atom, nbr, idx, W, stats, gated);
        // grid 625: 5 tiles/block exact; barrier-free body.
        k_apply<<<625, 256, 0, stream>>>(gated, g1, b1, stats, dout);
        k_final<<<512, 256, 0, stream>>>(atom, g2, b2, stats, dout);
    } else {
        k_zero<<<512, 256, 0, stream>>>(dout, stats);
        k_gemm_spill<false><<<750, 256, 0, stream>>>(atom, nbr, idx, W, stats, nullptr);
        k_gemm_main<<<1024, 256, 0, stream>>>(atom, nbr, idx, W, g1, b1, stats, dout);
        k_bn2_stats<<<256, 256, 0, stream>>>(dout, stats);
        k_final<<<512, 256, 0, stream>>>(atom, g2, b2, stats, dout);
    }
}